// Round 5
// baseline (233.445 us; speedup 1.0000x reference)
//
#include <hip/hip_runtime.h>

#define BLOCK 256
#define PAIRS 4   // float4-pairs per thread -> 8 dwordx4 loads in flight

__device__ __forceinline__ float gmgs_term(float pv, float tv, const float* __restrict__ sm_e) {
    // class = clip(floor(x), -1, 2) + 1  ->  {0,1,2,3}
    int pc = (int)fminf(fmaxf(floorf(pv), -1.0f), 2.0f) + 1;
    int tc = (int)fminf(fmaxf(floorf(tv), -1.0f), 2.0f) + 1;
    float d = pv - tv;
    return d * d * sm_e[(tc << 2) | pc];
}

__device__ __forceinline__ float gmgs_quad(float4 p, float4 t, const float* __restrict__ sm_e) {
    return (gmgs_term(p.x, t.x, sm_e) + gmgs_term(p.y, t.y, sm_e))
         + (gmgs_term(p.z, t.z, sm_e) + gmgs_term(p.w, t.w, sm_e));
}

// One-shot: each thread owns PAIRS float4-pairs, all loads issued before the
// barrier so the barrier's vmcnt(0) drain overlaps table-build with data
// latency. Per-block partial -> one atomicAdd (out zeroed by memsetAsync).
__global__ __launch_bounds__(BLOCK, 4) void gmgs_loss_kernel(
    const float4* __restrict__ pred4,
    const float4* __restrict__ tru4,
    const float* __restrict__ pred,
    const float* __restrict__ tru,
    const float* __restrict__ score,
    float* __restrict__ out,
    int n4, int rem, float invB)
{
    __shared__ float sm_e[16];
    __shared__ float sred[BLOCK / 64];

    const int tid  = threadIdx.x;
    const int base = (int)blockIdx.x * (BLOCK * PAIRS) + tid;

    // 1) issue all global data loads first (coalesced: stride BLOCK float4s)
    float4 p[PAIRS], t[PAIRS];
    bool inb[PAIRS];
    #pragma unroll
    for (int j = 0; j < PAIRS; ++j) {
        int i = base + j * BLOCK;
        inb[j] = (i < n4);
        int ic = inb[j] ? i : 0;
        p[j] = pred4[ic];
        t[j] = tru4[ic];
    }

    // 2) build the weight table under the load latency
    if (tid < 16) sm_e[tid] = expf(-score[tid]);
    __syncthreads();   // drains vmcnt too -> single latency exposure

    // 3) pure VALU + LDS-gather consumption
    float acc = 0.0f;
    #pragma unroll
    for (int j = 0; j < PAIRS; ++j)
        if (inb[j]) acc += gmgs_quad(p[j], t[j], sm_e);

    // scalar tail (n % 4) folded into block 0
    if (blockIdx.x == 0 && tid < rem) {
        int jj = n4 * 4 + tid;
        acc += gmgs_term(pred[jj], tru[jj], sm_e);
    }

    // block reduce
    #pragma unroll
    for (int off = 32; off > 0; off >>= 1)
        acc += __shfl_down(acc, off, 64);
    if ((tid & 63) == 0) sred[tid >> 6] = acc;
    __syncthreads();
    if (tid == 0) {
        float s = 0.0f;
        #pragma unroll
        for (int w = 0; w < BLOCK / 64; ++w) s += sred[w];
        float z = 0.0f;
        #pragma unroll
        for (int k = 0; k < 16; ++k) z += sm_e[k];
        atomicAdd(out, s * invB / z);
    }
}

extern "C" void kernel_launch(void* const* d_in, const int* in_sizes, int n_in,
                              void* d_out, int out_size, void* d_ws, size_t ws_size,
                              hipStream_t stream) {
    const float* pred  = (const float*)d_in[0];
    const float* tru   = (const float*)d_in[1];
    const float* score = (const float*)d_in[2];
    float* out = (float*)d_out;

    long long n = (long long)in_sizes[0];   // B*T*1
    int n4  = (int)(n >> 2);
    int rem = (int)(n & 3);
    long long B = n / 48;                   // T = 48 per problem setup
    float invB = 1.0f / (float)B;

    int nblk = (n4 + BLOCK * PAIRS - 1) / (BLOCK * PAIRS);   // 6144 for this shape

    hipMemsetAsync(d_out, 0, sizeof(float), stream);
    gmgs_loss_kernel<<<nblk, BLOCK, 0, stream>>>(
        (const float4*)pred, (const float4*)tru, pred, tru, score, out, n4, rem, invB);
}